// Round 5
// baseline (2343.633 us; speedup 1.0000x reference)
//
#include <hip/hip_runtime.h>

typedef unsigned short ushort_t;
typedef unsigned int   uint_t;

#define NTOK 50176          // B*D*Hp*Wp = 2*8*56*56
#define NWIN 98             // (8/4)*(56/8)*(56/8)
#define NBIAS 1575          // 7*15*15

typedef __attribute__((ext_vector_type(8))) short bf16x8;
typedef __attribute__((ext_vector_type(4))) float floatx4;

static __device__ __forceinline__ float lo2f(uint_t u) { return __uint_as_float(u << 16); }
static __device__ __forceinline__ float hi2f(uint_t u) { return __uint_as_float(u & 0xffff0000u); }
static __device__ __forceinline__ ushort_t f2b(float f) {
    union { float f; uint_t u; } v; v.f = f;
    uint_t u = v.u + 0x7fffu + ((v.u >> 16) & 1u);
    return (ushort_t)(u >> 16);
}

// token (B,D,Hp,Wp row-major) -> window-ordered index, with optional shift roll
static __device__ __forceinline__ int tok2wtok(int t, int sh) {
    int b = t / 25088, rem = t - b * 25088;
    int d = rem / 3136, r1 = rem - d * 3136;
    int h = r1 / 56, w = r1 - h * 56;
    if (sh) { d = (d + 6) & 7; h -= 4; if (h < 0) h += 56; w -= 4; if (w < 0) w += 56; }
    return ((b * 98 + (d >> 2) * 49 + (h >> 3) * 7 + (w >> 3)) << 8) |
           ((d & 3) << 6) | ((h & 7) << 3) | (w & 7);
}
static __device__ __forceinline__ int wtok2tok(int wt, int sh) {
    int b = wt / 25088, rem = wt - b * 25088;
    int win = rem >> 8, pos = rem & 255;
    int wd = win / 49, r1 = win - wd * 49;
    int wh = r1 / 7, ww = r1 - wh * 7;
    int d = wd * 4 + (pos >> 6), h = wh * 8 + ((pos >> 3) & 7), w = ww * 8 + (pos & 7);
    if (sh) { d = (d + 2) & 7; h += 4; if (h >= 56) h -= 56; w += 4; if (w >= 56) w -= 56; }
    return (b * 8 + d) * 3136 + h * 56 + w;
}

// ---------------- weight transpose + fp32->bf16 cast: dst[n*K+k] = bf16(src[k*N+n])
__global__ void transpose_w(const float* __restrict__ src, ushort_t* __restrict__ dst,
                            int K, int N) {
    long base = (long)blockIdx.y * K * N;
    int idx = blockIdx.x * 256 + threadIdx.x;
    if (idx < K * N) {
        int k = idx / N, n = idx - k * N;
        dst[base + (long)n * K + k] = f2b(src[base + idx]);
    }
}

// ---------------- elementwise fp32 -> bf16 cast
__global__ void cast_bf16(const float* __restrict__ src, ushort_t* __restrict__ dst, int n) {
    int i = blockIdx.x * 256 + threadIdx.x;
    if (i < n) dst[i] = f2b(src[i]);
}

// ---------------- expand relative-position bias: Bx[layer][hd][key j][query i] fp32
__global__ void expand_bias(const float* __restrict__ bias_tab, float* __restrict__ Bx) {
    int j = blockIdx.x, hd = blockIdx.y, l = blockIdx.z;
    int i = threadIdx.x;
    int rd = (i >> 6) - (j >> 6) + 3;
    int rh = ((i >> 3) & 7) - ((j >> 3) & 7) + 7;
    int rw = (i & 7) - (j & 7) + 7;
    int idx = rd * 225 + rh * 15 + rw;
    Bx[((((size_t)l * 8 + hd) << 8) + j) * 256 + i] = bias_tab[((size_t)l * NBIAS + idx) * 8 + hd];
}

// ---------------- im2row: A[tok, 64] bf16 patch matrix from X (NCDHW fp32)
__global__ void im2row(const float* __restrict__ X, ushort_t* __restrict__ A) {
    int idx = blockIdx.x * 256 + threadIdx.x;   // NTOK*16 total
    int t = idx >> 4;
    int k = idx & 15;
    int ic = k >> 2, kh = k & 3;
    int w = t % 56, h = (t / 56) % 56, d = (t / 3136) % 8, b = t / 25088;
    long xi = (((long)(b * 4 + ic) * 8 + d) * 224 + (h * 4 + kh)) * 224 + w * 4;
    float4 u = *(const float4*)(X + xi);
    ushort_t* ap = A + (long)t * 64 + ic * 16 + kh * 4;
    ap[0] = f2b(u.x); ap[1] = f2b(u.y); ap[2] = f2b(u.z); ap[3] = f2b(u.w);
}

// ---------------- LayerNorm: 4 tokens per block, one wave per token; fp32 in, bf16 out
__global__ void ln_kernel(const float* __restrict__ Y, ushort_t* __restrict__ Xn,
                          const float* __restrict__ S, const float* __restrict__ Bb) {
    int wv = threadIdx.x >> 6, lane = threadIdx.x & 63;
    long t = (long)blockIdx.x * 4 + wv;
    const float* y = Y + t * 256;
    float v[4], s = 0.f, s2 = 0.f;
#pragma unroll
    for (int r = 0; r < 4; ++r) { v[r] = y[lane + 64 * r]; s += v[r]; s2 += v[r] * v[r]; }
#pragma unroll
    for (int off = 32; off; off >>= 1) { s += __shfl_xor(s, off, 64); s2 += __shfl_xor(s2, off, 64); }
    float mu = s * (1.f / 256.f);
    float var = s2 * (1.f / 256.f) - mu * mu;
    float rstd = rsqrtf(var + 1e-5f);
#pragma unroll
    for (int r = 0; r < 4; ++r) {
        int c = lane + 64 * r;
        Xn[t * 256 + c] = f2b((v[r] - mu) * rstd * S[c] + Bb[c]);
    }
}

// ---------------- GEMM: C[M,N] = A[M,K] @ B[K,N] via BT[N,K]; m97-style 128x128 tile
// mode 0: bf16 store; 1: bias+gelu bf16; 2: Y += acc+bias (fp32); 3: Y = acc+bias (fp32);
// 4: QKV scatter to head-split window-ordered [mat*8+hd][NTOK][32] (rows permuted by sh);
// 5: Y[tok] += acc+bias with row un-permute (A rows are window-ordered)
__global__ __launch_bounds__(256, 2) void gemm_bt(
    const ushort_t* __restrict__ A, const ushort_t* __restrict__ BT,
    int M, int N, int K,
    const float* __restrict__ bias, int mode,
    ushort_t* __restrict__ C, float* __restrict__ Y, int sh) {
    __shared__ ushort_t As[128 * 32];
    __shared__ ushort_t Bs[128 * 32];
    const int tid = threadIdx.x;
    const int wv = tid >> 6;
    const int lane = tid & 63;
    const int quad = lane >> 4;
    const int l15 = lane & 15;
    const long m0 = (long)blockIdx.x * 128;
    const long n0 = (long)blockIdx.y * 128;
    const int wm = (wv & 1) * 64;
    const int wn = (wv >> 1) * 64;
    const int r_loc = lane >> 2;
    const int k_loc = (lane & 3) * 8;

    floatx4 acc[4][4] = {};

    const ushort_t* Ab = A + m0 * K;
    const ushort_t* Bb = BT + n0 * K;

    for (int kt = 0; kt < K; kt += 32) {
#pragma unroll
        for (int q = 0; q < 2; ++q) {
            int slot = wv * 2 + q;
            int row = slot * 16 + r_loc;
            __builtin_amdgcn_global_load_lds(
                (const __attribute__((address_space(1))) void*)(Ab + (long)row * K + kt + k_loc),
                (__attribute__((address_space(3))) void*)(As + slot * 512), 16, 0, 0);
            __builtin_amdgcn_global_load_lds(
                (const __attribute__((address_space(1))) void*)(Bb + (long)row * K + kt + k_loc),
                (__attribute__((address_space(3))) void*)(Bs + slot * 512), 16, 0, 0);
        }
        __syncthreads();
        bf16x8 af[4], bfr[4];
#pragma unroll
        for (int i = 0; i < 4; ++i) {
            af[i]  = *(const bf16x8*)(As + (wm + i * 16 + l15) * 32 + quad * 8);
            bfr[i] = *(const bf16x8*)(Bs + (wn + i * 16 + l15) * 32 + quad * 8);
        }
#pragma unroll
        for (int mi = 0; mi < 4; ++mi)
#pragma unroll
            for (int ni = 0; ni < 4; ++ni)
                acc[mi][ni] = __builtin_amdgcn_mfma_f32_16x16x32_bf16(af[mi], bfr[ni], acc[mi][ni], 0, 0, 0);
        __syncthreads();
    }

    if (mode == 2) {
#pragma unroll
        for (int mi = 0; mi < 4; ++mi)
#pragma unroll
            for (int ni = 0; ni < 4; ++ni) {
                long col = n0 + wn + ni * 16 + l15;
                float bv = bias[col];
#pragma unroll
                for (int r = 0; r < 4; ++r) {
                    long row = m0 + wm + mi * 16 + quad * 4 + r;
                    Y[row * N + col] += acc[mi][ni][r] + bv;
                }
            }
    } else if (mode == 3) {
#pragma unroll
        for (int mi = 0; mi < 4; ++mi)
#pragma unroll
            for (int ni = 0; ni < 4; ++ni) {
                long col = n0 + wn + ni * 16 + l15;
                float bv = bias[col];
#pragma unroll
                for (int r = 0; r < 4; ++r) {
                    long row = m0 + wm + mi * 16 + quad * 4 + r;
                    Y[row * N + col] = acc[mi][ni][r] + bv;
                }
            }
    } else if (mode == 4) {
#pragma unroll
        for (int mi = 0; mi < 4; ++mi) {
            int wt[4];
#pragma unroll
            for (int r = 0; r < 4; ++r)
                wt[r] = tok2wtok((int)(m0 + wm + mi * 16 + quad * 4 + r), sh);
#pragma unroll
            for (int ni = 0; ni < 4; ++ni) {
                int c = (int)(n0 + wn + ni * 16 + l15);
                int mat = c >> 8, hh = (c >> 5) & 7, ch = c & 31;
                size_t pb = ((size_t)(mat * 8 + hh) * NTOK) * 32 + ch;
#pragma unroll
                for (int r = 0; r < 4; ++r)
                    C[pb + (size_t)wt[r] * 32] = f2b(acc[mi][ni][r]);
            }
        }
    } else if (mode == 5) {
#pragma unroll
        for (int mi = 0; mi < 4; ++mi) {
            int tk[4];
#pragma unroll
            for (int r = 0; r < 4; ++r)
                tk[r] = wtok2tok((int)(m0 + wm + mi * 16 + quad * 4 + r), sh);
#pragma unroll
            for (int ni = 0; ni < 4; ++ni) {
                long col = n0 + wn + ni * 16 + l15;
                float bv = bias[col];
#pragma unroll
                for (int r = 0; r < 4; ++r)
                    Y[(size_t)tk[r] * N + col] += acc[mi][ni][r] + bv;
            }
        }
    } else {
#pragma unroll
        for (int mi = 0; mi < 4; ++mi)
#pragma unroll
            for (int ni = 0; ni < 4; ++ni) {
                long col = n0 + wn + ni * 16 + l15;
                float bv = bias ? bias[col] : 0.f;
#pragma unroll
                for (int r = 0; r < 4; ++r) {
                    long row = m0 + wm + mi * 16 + quad * 4 + r;
                    float v = acc[mi][ni][r] + bv;
                    if (mode == 1) {
                        float x3 = v * v * v;
                        v = 0.5f * v * (1.f + tanhf(0.7978845608028654f * (v + 0.044715f * x3)));
                    }
                    C[row * N + col] = f2b(v);
                }
            }
    }
}

// ---------------- MFMA window attention v2: S^T layout, no P round-trip.
// QKV head-split window-ordered [mat*8+hd][wtok][32]; O window-ordered [wtok][256].
#define VTS 268
__global__ __launch_bounds__(256, 4) void attn_mfma(
    const ushort_t* __restrict__ QKV, ushort_t* __restrict__ O,
    const float* __restrict__ Bx, int shifted) {
    __shared__ ushort_t Ks[256 * 32];      // K [tok][32]
    __shared__ ushort_t Vt[32 * VTS];      // V^T [ch][tok]
    __shared__ int reg_s[256];

    const int tid = threadIdx.x;
    const int wv = tid >> 6;
    const int lane = tid & 63;
    const int quad = lane >> 4;
    const int l15 = lane & 15;
    const int win = blockIdx.x, hd = blockIdx.y, b = blockIdx.z;
    const int wd = win / 49, r1w = win - wd * 49;
    const int wh = r1w / 7, ww = r1w - wh * 7;
    const size_t wbase = ((size_t)b * 98 + win) * 256;
    const ushort_t* Qg = QKV + ((size_t)hd * NTOK + wbase) * 32;
    const ushort_t* Kg = QKV + ((size_t)(8 + hd) * NTOK + wbase) * 32;
    const ushort_t* Vg = QKV + ((size_t)(16 + hd) * NTOK + wbase) * 32;

    {   // region ids (rolled coords)
        int pos = tid;
        int d = wd * 4 + (pos >> 6), h = wh * 8 + ((pos >> 3) & 7), w = ww * 8 + (pos & 7);
        int rd = d < 4 ? 0 : (d < 6 ? 1 : 2);
        int rh = h < 48 ? 0 : (h < 52 ? 1 : 2);
        int rw = w < 48 ? 0 : (w < 52 ? 1 : 2);
        reg_s[pos] = rd * 9 + rh * 3 + rw;
    }
    {   // stage K via async load (contiguous 16 KB)
#pragma unroll
        for (int q = 0; q < 4; ++q) {
            int off = wv * 2048 + q * 512;     // shorts
            __builtin_amdgcn_global_load_lds(
                (const __attribute__((address_space(1))) void*)(Kg + off + lane * 8),
                (__attribute__((address_space(3))) void*)(Ks + off), 16, 0, 0);
        }
        // stage V^T (coalesced read, scatter to LDS)
        const uint4* vsrc = (const uint4*)Vg;
#pragma unroll
        for (int p = 0; p < 4; ++p) {
            int u = tid + p * 256;
            uint4 vv = vsrc[u];
            int tok = u >> 2, chb = (u & 3) * 8;
            uint_t uu[4] = {vv.x, vv.y, vv.z, vv.w};
#pragma unroll
            for (int e = 0; e < 4; ++e) {
                Vt[(chb + 2 * e) * VTS + tok]     = (ushort_t)(uu[e] & 0xffffu);
                Vt[(chb + 2 * e + 1) * VTS + tok] = (ushort_t)(uu[e] >> 16);
            }
        }
    }
    __syncthreads();

    const int hm = shifted && (wd == 1 || wh == 6 || ww == 6);
    const float scale = 0.17677669529663687f;
    const float* bb = Bx + ((size_t)hd << 16) + l15;

    for (int rg = 0; rg < 4; ++rg) {
        const int q0 = (wv * 4 + rg) * 16;
        bf16x8 aq = *(const bf16x8*)(Qg + (size_t)(q0 + l15) * 32 + quad * 8);
        // S^T = K @ Q^T : row = key, col = query
        floatx4 Sc[16];
#pragma unroll
        for (int nt = 0; nt < 16; ++nt) {
            bf16x8 bk = *(const bf16x8*)(Ks + (nt * 16 + l15) * 32 + quad * 8);
            floatx4 z = {};
            Sc[nt] = __builtin_amdgcn_mfma_f32_16x16x32_bf16(bk, aq, z, 0, 0, 0);
        }
        float mx = -3e38f;
        const float* bq = bb + q0;
        if (!hm) {
#pragma unroll
            for (int nt = 0; nt < 16; ++nt)
#pragma unroll
                for (int r = 0; r < 4; ++r) {
                    float s = fmaf(Sc[nt][r], scale, bq[(nt * 16 + quad * 4 + r) << 8]);
                    Sc[nt][r] = s; mx = fmaxf(mx, s);
                }
        } else {
            int myreg = reg_s[q0 + l15];
#pragma unroll
            for (int nt = 0; nt < 16; ++nt)
#pragma unroll
                for (int r = 0; r < 4; ++r) {
                    int key = nt * 16 + quad * 4 + r;
                    float s = fmaf(Sc[nt][r], scale, bq[key << 8]);
                    s = (reg_s[key] == myreg) ? s : -1e9f;
                    Sc[nt][r] = s; mx = fmaxf(mx, s);
                }
        }
        mx = fmaxf(mx, __shfl_xor(mx, 16, 64));
        mx = fmaxf(mx, __shfl_xor(mx, 32, 64));
        float lsum = 0.f;
#pragma unroll
        for (int nt = 0; nt < 16; ++nt)
#pragma unroll
            for (int r = 0; r < 4; ++r) {
                float p = __expf(Sc[nt][r] - mx);
                lsum += p; Sc[nt][r] = p;
            }
        lsum += __shfl_xor(lsum, 16, 64);
        lsum += __shfl_xor(lsum, 32, 64);
        float inv = 1.f / lsum;
        // O^T = V^T @ P^T : one 16x16x32 mfma per 32 keys (tiles 2kt,2kt+1),
        // lane-local bijection k-slot (quad,j): j<4 -> tileA key quad*4+j, j>=4 -> tileB.
        floatx4 oc[2] = {{0.f,0.f,0.f,0.f},{0.f,0.f,0.f,0.f}};
        const ushort_t* vr = Vt + quad * 4;
#pragma unroll
        for (int kt = 0; kt < 8; ++kt) {
            union { uint_t u[4]; bf16x8 v; } bp;
            bp.u[0] = __builtin_amdgcn_perm(__float_as_uint(Sc[2*kt][1]),   __float_as_uint(Sc[2*kt][0]),   0x07060302u);
            bp.u[1] = __builtin_amdgcn_perm(__float_as_uint(Sc[2*kt][3]),   __float_as_uint(Sc[2*kt][2]),   0x07060302u);
            bp.u[2] = __builtin_amdgcn_perm(__float_as_uint(Sc[2*kt+1][1]), __float_as_uint(Sc[2*kt+1][0]), 0x07060302u);
            bp.u[3] = __builtin_amdgcn_perm(__float_as_uint(Sc[2*kt+1][3]), __float_as_uint(Sc[2*kt+1][2]), 0x07060302u);
#pragma unroll
            for (int ct = 0; ct < 2; ++ct) {
                const ushort_t* vrow = vr + (ct * 16 + l15) * VTS;
                union { unsigned long long l[2]; bf16x8 v; } av;
                av.l[0] = *(const unsigned long long*)(vrow + 2 * kt * 16);
                av.l[1] = *(const unsigned long long*)(vrow + 2 * kt * 16 + 16);
                oc[ct] = __builtin_amdgcn_mfma_f32_16x16x32_bf16(av.v, bp.v, oc[ct], 0, 0, 0);
            }
        }
        size_t obase = (wbase + q0 + l15) * 256 + hd * 32 + quad * 4;
#pragma unroll
        for (int ct = 0; ct < 2; ++ct) {
            uint2 st;
            st.x = (uint_t)f2b(oc[ct][0] * inv) | ((uint_t)f2b(oc[ct][1] * inv) << 16);
            st.y = (uint_t)f2b(oc[ct][2] * inv) | ((uint_t)f2b(oc[ct][3] * inv) << 16);
            *(uint2*)(O + obase + ct * 16) = st;
        }
    }
}

// ---------------- final permute: y (tok, C) fp32 -> out (B, C, D, Hp, Wp) fp32
__global__ void out_permute(const float* __restrict__ Y, float* __restrict__ Out) {
    __shared__ float tile[64][65];
    const int t0 = blockIdx.x * 64;
    const int c0 = blockIdx.y * 64;
    const int tid = threadIdx.x;
    const int a = tid >> 6;
    const int bx = tid & 63;
#pragma unroll
    for (int s8 = 0; s8 < 16; ++s8) {
        int tt = a + s8 * 4;
        tile[tt][bx] = Y[(long)(t0 + tt) * 256 + c0 + bx];
    }
    __syncthreads();
#pragma unroll
    for (int s8 = 0; s8 < 16; ++s8) {
        int cc = a + s8 * 4;
        int tok = t0 + bx;
        int bb = tok / 25088;
        int rem = tok - bb * 25088;
        Out[((long)(bb * 256 + c0 + cc)) * 25088 + rem] = tile[bx][cc];
    }
}

extern "C" void kernel_launch(void* const* d_in, const int* in_sizes, int n_in,
                              void* d_out, int out_size, void* d_ws, size_t ws_size,
                              hipStream_t stream) {
    (void)in_sizes; (void)n_in; (void)out_size; (void)ws_size;
    const float* x        = (const float*)d_in[0];
    const float* conv_w   = (const float*)d_in[1];
    const float* conv_b   = (const float*)d_in[2];
    const float* ln1_s    = (const float*)d_in[3];
    const float* ln1_b    = (const float*)d_in[4];
    const float* qkv_w    = (const float*)d_in[5];
    const float* out_w    = (const float*)d_in[6];
    const float* out_b    = (const float*)d_in[7];
    const float* bias_tab = (const float*)d_in[8];
    const float* ln2_s    = (const float*)d_in[9];
    const float* ln2_b    = (const float*)d_in[10];
    const float* fc1_w    = (const float*)d_in[11];
    const float* fc1_b    = (const float*)d_in[12];
    const float* fc2_w    = (const float*)d_in[13];
    const float* fc2_b    = (const float*)d_in[14];
    float* out = (float*)d_out;

    char* ws = (char*)d_ws;
    float*    y    = (float*)ws;    ws += (size_t)NTOK * 256 * 4;   // fp32 residual stream
    ushort_t* big  = (ushort_t*)ws; ws += (size_t)NTOK * 1024 * 2;  // qkv(head-split)/h1/im2row
    ushort_t* xob  = (ushort_t*)ws; ws += (size_t)NTOK * 256 * 2;   // LN out / attn out bf16
    ushort_t* bt_qkv = (ushort_t*)ws; ws += (size_t)4 * 768 * 256 * 2;
    ushort_t* bt_out = (ushort_t*)ws; ws += (size_t)4 * 256 * 256 * 2;
    ushort_t* bt_fc1 = (ushort_t*)ws; ws += (size_t)4 * 1024 * 256 * 2;
    ushort_t* bt_fc2 = (ushort_t*)ws; ws += (size_t)4 * 256 * 1024 * 2;
    ushort_t* cw_bf  = (ushort_t*)ws; ws += (size_t)256 * 64 * 2;
    float*    Bx     = (float*)ws;  ws += (size_t)4 * 8 * 256 * 256 * 4;

    transpose_w<<<dim3((256 * 768 + 255) / 256, 4), 256, 0, stream>>>(qkv_w, bt_qkv, 256, 768);
    transpose_w<<<dim3((256 * 256 + 255) / 256, 4), 256, 0, stream>>>(out_w, bt_out, 256, 256);
    transpose_w<<<dim3((256 * 1024 + 255) / 256, 4), 256, 0, stream>>>(fc1_w, bt_fc1, 256, 1024);
    transpose_w<<<dim3((1024 * 256 + 255) / 256, 4), 256, 0, stream>>>(fc2_w, bt_fc2, 1024, 256);
    expand_bias<<<dim3(256, 8, 4), 256, 0, stream>>>(bias_tab, Bx);

    // conv as GEMM: conv_w (O,I,1,4,4) is already BT[256][64] row-major — cast only
    cast_bf16<<<(256 * 64 + 255) / 256, 256, 0, stream>>>(conv_w, cw_bf, 256 * 64);
    im2row<<<NTOK * 16 / 256, 256, 0, stream>>>(x, big);
    gemm_bt<<<dim3(NTOK / 128, 2), 256, 0, stream>>>(
        big, cw_bf, NTOK, 256, 64, conv_b, 3, nullptr, y, 0);

    for (int i = 0; i < 4; ++i) {
        int sh = i & 1;
        ln_kernel<<<NTOK / 4, 256, 0, stream>>>(y, xob, ln1_s + i * 256, ln1_b + i * 256);
        // QKV, scattered into head-split window-ordered layout
        gemm_bt<<<dim3(NTOK / 128, 6), 256, 0, stream>>>(
            xob, bt_qkv + (size_t)i * 768 * 256, NTOK, 768, 256, nullptr, 4, big, nullptr, sh);
        attn_mfma<<<dim3(NWIN, 8, 2), 256, 0, stream>>>(
            big, xob, Bx + (size_t)i * 8 * 65536, sh);
        // out-proj: A is window-ordered, un-permute rows into y
        gemm_bt<<<dim3(NTOK / 128, 2), 256, 0, stream>>>(
            xob, bt_out + (size_t)i * 256 * 256, NTOK, 256, 256, out_b + i * 256, 5, nullptr, y, sh);
        ln_kernel<<<NTOK / 4, 256, 0, stream>>>(y, xob, ln2_s + i * 256, ln2_b + i * 256);
        gemm_bt<<<dim3(NTOK / 128, 8), 256, 0, stream>>>(
            xob, bt_fc1 + (size_t)i * 1024 * 256, NTOK, 1024, 256, fc1_b + i * 1024, 1, big, nullptr, 0);
        gemm_bt<<<dim3(NTOK / 128, 2), 256, 0, stream>>>(
            big, bt_fc2 + (size_t)i * 256 * 1024, NTOK, 256, 1024, fc2_b + i * 256, 2, nullptr, y, 0);
    }

    out_permute<<<dim3(NTOK / 64, 4), 256, 0, stream>>>(y, out);
}

// Round 6
// 1564.071 us; speedup vs baseline: 1.4984x; 1.4984x over previous
//
#include <hip/hip_runtime.h>

typedef unsigned short ushort_t;
typedef unsigned int   uint_t;

#define NTOK 50176          // B*D*Hp*Wp = 2*8*56*56
#define NWIN 98             // (8/4)*(56/8)*(56/8)
#define NBIAS 1575          // 7*15*15

typedef __attribute__((ext_vector_type(8))) short bf16x8;
typedef __attribute__((ext_vector_type(4))) float floatx4;

static __device__ __forceinline__ float b2f(ushort_t u) {
    return __uint_as_float(((uint_t)u) << 16);
}
static __device__ __forceinline__ ushort_t f2b(float f) {
    union { float f; uint_t u; } v; v.f = f;
    uint_t u = v.u + 0x7fffu + ((v.u >> 16) & 1u);
    return (ushort_t)(u >> 16);
}

// window-ordered index -> token (B,D,Hp,Wp row-major), with optional shift roll
static __device__ __forceinline__ int wtok2tok(int wt, int sh) {
    int b = wt / 25088, rem = wt - b * 25088;
    int win = rem >> 8, pos = rem & 255;
    int wd = win / 49, r1 = win - wd * 49;
    int wh = r1 / 7, ww = r1 - wh * 7;
    int d = wd * 4 + (pos >> 6), h = wh * 8 + ((pos >> 3) & 7), w = ww * 8 + (pos & 7);
    if (sh) { d = (d + 2) & 7; h += 4; if (h >= 56) h -= 56; w += 4; if (w >= 56) w -= 56; }
    return (b * 8 + d) * 3136 + h * 56 + w;
}

// ---------------- weight transpose + fp32->bf16 cast: dst[n*K+k] = bf16(src[k*N+n])
__global__ void transpose_w(const float* __restrict__ src, ushort_t* __restrict__ dst,
                            int K, int N) {
    long base = (long)blockIdx.y * K * N;
    int idx = blockIdx.x * 256 + threadIdx.x;
    if (idx < K * N) {
        int k = idx / N, n = idx - k * N;
        dst[base + (long)n * K + k] = f2b(src[base + idx]);
    }
}

// ---------------- elementwise fp32 -> bf16 cast
__global__ void cast_bf16(const float* __restrict__ src, ushort_t* __restrict__ dst, int n) {
    int i = blockIdx.x * 256 + threadIdx.x;
    if (i < n) dst[i] = f2b(src[i]);
}

// ---------------- expand relative-position bias: Bx[layer][hd][key j][query i] bf16
__global__ void expand_bias(const float* __restrict__ bias_tab, ushort_t* __restrict__ Bx) {
    int j = blockIdx.x, hd = blockIdx.y, l = blockIdx.z;
    int i = threadIdx.x;
    int rd = (i >> 6) - (j >> 6) + 3;
    int rh = ((i >> 3) & 7) - ((j >> 3) & 7) + 7;
    int rw = (i & 7) - (j & 7) + 7;
    int idx = rd * 225 + rh * 15 + rw;
    Bx[((((size_t)l * 8 + hd) << 8) + j) * 256 + i] =
        f2b(bias_tab[((size_t)l * NBIAS + idx) * 8 + hd]);
}

// ---------------- im2row: A[tok, 64] bf16 patch matrix from X (NCDHW fp32)
__global__ void im2row(const float* __restrict__ X, ushort_t* __restrict__ A) {
    int idx = blockIdx.x * 256 + threadIdx.x;   // NTOK*16 total
    int t = idx >> 4;
    int k = idx & 15;
    int ic = k >> 2, kh = k & 3;
    int w = t % 56, h = (t / 56) % 56, d = (t / 3136) % 8, b = t / 25088;
    long xi = (((long)(b * 4 + ic) * 8 + d) * 224 + (h * 4 + kh)) * 224 + w * 4;
    float4 u = *(const float4*)(X + xi);
    ushort_t* ap = A + (long)t * 64 + ic * 16 + kh * 4;
    ap[0] = f2b(u.x); ap[1] = f2b(u.y); ap[2] = f2b(u.z); ap[3] = f2b(u.w);
}

// ---------------- LayerNorm: 4 tokens per block, one wave per token; fp32 in, bf16 out
__global__ void ln_kernel(const float* __restrict__ Y, ushort_t* __restrict__ Xn,
                          const float* __restrict__ S, const float* __restrict__ Bb) {
    int wv = threadIdx.x >> 6, lane = threadIdx.x & 63;
    long t = (long)blockIdx.x * 4 + wv;
    const float* y = Y + t * 256;
    float v[4], s = 0.f, s2 = 0.f;
#pragma unroll
    for (int r = 0; r < 4; ++r) { v[r] = y[lane + 64 * r]; s += v[r]; s2 += v[r] * v[r]; }
#pragma unroll
    for (int off = 32; off; off >>= 1) { s += __shfl_xor(s, off, 64); s2 += __shfl_xor(s2, off, 64); }
    float mu = s * (1.f / 256.f);
    float var = s2 * (1.f / 256.f) - mu * mu;
    float rstd = rsqrtf(var + 1e-5f);
#pragma unroll
    for (int r = 0; r < 4; ++r) {
        int c = lane + 64 * r;
        Xn[t * 256 + c] = f2b((v[r] - mu) * rstd * S[c] + Bb[c]);
    }
}

// ---------------- GEMM: C[M,N] = A[M,K] @ B[K,N] via BT[N,K]; m97-style 128x128 tile
// mode 0: bf16 store; 1: bias+gelu bf16; 2: Y += acc+bias (fp32); 3: Y = acc+bias (fp32);
// 5: Y[tok] += acc+bias, rows un-permuted from window order (sh)
// asplit: A stored head-split [c>>5][NTOK][32] instead of row-major [M][K]
__global__ __launch_bounds__(256, 2) void gemm_bt(
    const ushort_t* __restrict__ A, const ushort_t* __restrict__ BT,
    int M, int N, int K,
    const float* __restrict__ bias, int mode,
    ushort_t* __restrict__ C, float* __restrict__ Y, int sh, int asplit) {
    __shared__ ushort_t As[128 * 32];
    __shared__ ushort_t Bs[128 * 32];
    const int tid = threadIdx.x;
    const int wv = tid >> 6;
    const int lane = tid & 63;
    const int quad = lane >> 4;
    const int l15 = lane & 15;
    const long m0 = (long)blockIdx.x * 128;
    const long n0 = (long)blockIdx.y * 128;
    const int wm = (wv & 1) * 64;
    const int wn = (wv >> 1) * 64;
    const int r_loc = lane >> 2;
    const int k_loc = (lane & 3) * 8;

    floatx4 acc[4][4] = {};

    const ushort_t* Ab = A + m0 * K;
    const ushort_t* Bb = BT + n0 * K;

    for (int kt = 0; kt < K; kt += 32) {
#pragma unroll
        for (int q = 0; q < 2; ++q) {
            int slot = wv * 2 + q;
            int row = slot * 16 + r_loc;
            const ushort_t* asrc = asplit
                ? A + ((size_t)(kt >> 5) * NTOK + m0 + row) * 32 + k_loc
                : Ab + (long)row * K + kt + k_loc;
            __builtin_amdgcn_global_load_lds(
                (const __attribute__((address_space(1))) void*)asrc,
                (__attribute__((address_space(3))) void*)(As + slot * 512), 16, 0, 0);
            __builtin_amdgcn_global_load_lds(
                (const __attribute__((address_space(1))) void*)(Bb + (long)row * K + kt + k_loc),
                (__attribute__((address_space(3))) void*)(Bs + slot * 512), 16, 0, 0);
        }
        __syncthreads();
        bf16x8 af[4], bfr[4];
#pragma unroll
        for (int i = 0; i < 4; ++i) {
            af[i]  = *(const bf16x8*)(As + (wm + i * 16 + l15) * 32 + quad * 8);
            bfr[i] = *(const bf16x8*)(Bs + (wn + i * 16 + l15) * 32 + quad * 8);
        }
#pragma unroll
        for (int mi = 0; mi < 4; ++mi)
#pragma unroll
            for (int ni = 0; ni < 4; ++ni)
                acc[mi][ni] = __builtin_amdgcn_mfma_f32_16x16x32_bf16(af[mi], bfr[ni], acc[mi][ni], 0, 0, 0);
        __syncthreads();
    }

    if (mode == 2) {
#pragma unroll
        for (int mi = 0; mi < 4; ++mi)
#pragma unroll
            for (int ni = 0; ni < 4; ++ni) {
                long col = n0 + wn + ni * 16 + l15;
                float bv = bias[col];
#pragma unroll
                for (int r = 0; r < 4; ++r) {
                    long row = m0 + wm + mi * 16 + quad * 4 + r;
                    Y[row * N + col] += acc[mi][ni][r] + bv;
                }
            }
    } else if (mode == 3) {
#pragma unroll
        for (int mi = 0; mi < 4; ++mi)
#pragma unroll
            for (int ni = 0; ni < 4; ++ni) {
                long col = n0 + wn + ni * 16 + l15;
                float bv = bias[col];
#pragma unroll
                for (int r = 0; r < 4; ++r) {
                    long row = m0 + wm + mi * 16 + quad * 4 + r;
                    Y[row * N + col] = acc[mi][ni][r] + bv;
                }
            }
    } else if (mode == 5) {
#pragma unroll
        for (int mi = 0; mi < 4; ++mi) {
            int tk[4];
#pragma unroll
            for (int r = 0; r < 4; ++r)
                tk[r] = wtok2tok((int)(m0 + wm + mi * 16 + quad * 4 + r), sh);
#pragma unroll
            for (int ni = 0; ni < 4; ++ni) {
                long col = n0 + wn + ni * 16 + l15;
                float bv = bias[col];
#pragma unroll
                for (int r = 0; r < 4; ++r)
                    Y[(size_t)tk[r] * N + col] += acc[mi][ni][r] + bv;
            }
        }
    } else {
#pragma unroll
        for (int mi = 0; mi < 4; ++mi)
#pragma unroll
            for (int ni = 0; ni < 4; ++ni) {
                long col = n0 + wn + ni * 16 + l15;
                float bv = bias ? bias[col] : 0.f;
#pragma unroll
                for (int r = 0; r < 4; ++r) {
                    long row = m0 + wm + mi * 16 + quad * 4 + r;
                    float v = acc[mi][ni][r] + bv;
                    if (mode == 1) {
                        float x3 = v * v * v;
                        v = 0.5f * v * (1.f + tanhf(0.7978845608028654f * (v + 0.044715f * x3)));
                    }
                    C[row * N + col] = f2b(v);
                }
            }
    }
}

// ---------------- MFMA window attention v3: S^T layout, gather staging, coalesced O.
// QKV plain [tok][768]; O head-split window-ordered [hd][NTOK][32]; Bx bf16.
#define VTS 268
#define OLS 34
__global__ __launch_bounds__(256, 4) void attn_mfma(
    const ushort_t* __restrict__ QKV, ushort_t* __restrict__ O,
    const ushort_t* __restrict__ Bx, int shifted) {
    __shared__ ushort_t Ks[256 * 32];      // K [tok][32]
    __shared__ ushort_t Vt[32 * VTS];      // V^T [ch][tok]
    __shared__ ushort_t Ol[4 * 16 * OLS];  // per-wave O staging
    __shared__ int tok_s[256];
    __shared__ int reg_s[256];

    const int tid = threadIdx.x;
    const int wv = tid >> 6;
    const int lane = tid & 63;
    const int quad = lane >> 4;
    const int l15 = lane & 15;
    const int win = blockIdx.x, hd = blockIdx.y, b = blockIdx.z;
    const int wd = win / 49, r1w = win - wd * 49;
    const int wh = r1w / 7, ww = r1w - wh * 7;
    const size_t wbase = ((size_t)b * 98 + win) * 256;

    {   // token ids (with shift roll) + region ids
        int pos = tid;
        int d = wd * 4 + (pos >> 6), h = wh * 8 + ((pos >> 3) & 7), w = ww * 8 + (pos & 7);
        int rd = d < 4 ? 0 : (d < 6 ? 1 : 2);
        int rh = h < 48 ? 0 : (h < 52 ? 1 : 2);
        int rw = w < 48 ? 0 : (w < 52 ? 1 : 2);
        reg_s[pos] = rd * 9 + rh * 3 + rw;
        int d0 = d, h0 = h, w0 = w;
        if (shifted) { d0 = (d + 2) & 7; h0 = h + 4; if (h0 >= 56) h0 -= 56; w0 = w + 4; if (w0 >= 56) w0 -= 56; }
        tok_s[pos] = (b * 8 + d0) * 3136 + h0 * 56 + w0;
    }
    __syncthreads();
    {   // stage K via global_load_lds: lane -> token (grp + lane>>2), 16B chunk (lane&3)
#pragma unroll
        for (int q = 0; q < 4; ++q) {
            int t = wv * 64 + q * 16 + (lane >> 2);
            const ushort_t* src = QKV + (size_t)tok_s[t] * 768 + 256 + hd * 32 + (lane & 3) * 8;
            __builtin_amdgcn_global_load_lds(
                (const __attribute__((address_space(1))) void*)src,
                (__attribute__((address_space(3))) void*)(Ks + wv * 2048 + q * 512), 16, 0, 0);
        }
        // stage V^T: coalesced-ish 16B reads, scatter to LDS
#pragma unroll
        for (int p = 0; p < 4; ++p) {
            int u = tid + p * 256;
            int tok = u >> 2, chb = (u & 3) * 8;
            uint4 vv = *(const uint4*)(QKV + (size_t)tok_s[tok] * 768 + 512 + hd * 32 + chb);
            uint_t uu[4] = {vv.x, vv.y, vv.z, vv.w};
#pragma unroll
            for (int e = 0; e < 4; ++e) {
                Vt[(chb + 2 * e) * VTS + tok]     = (ushort_t)(uu[e] & 0xffffu);
                Vt[(chb + 2 * e + 1) * VTS + tok] = (ushort_t)(uu[e] >> 16);
            }
        }
    }
    __syncthreads();

    const int hm = shifted && (wd == 1 || wh == 6 || ww == 6);
    const float scale = 0.17677669529663687f;
    const ushort_t* bb = Bx + ((size_t)hd << 16) + l15;
    ushort_t* ow = Ol + wv * 16 * OLS;
    ushort_t* Og = O + ((size_t)hd * NTOK + wbase) * 32;

    for (int rg = 0; rg < 4; ++rg) {
        const int q0 = (wv * 4 + rg) * 16;
        bf16x8 aq;
        {
            union { uint4 u; bf16x8 v; } cv;
            cv.u = *(const uint4*)(QKV + (size_t)tok_s[q0 + l15] * 768 + hd * 32 + quad * 8);
            aq = cv.v;
        }
        // S^T = K @ Q^T : row = key, col = query
        floatx4 Sc[16];
#pragma unroll
        for (int nt = 0; nt < 16; ++nt) {
            bf16x8 bk = *(const bf16x8*)(Ks + (nt * 16 + l15) * 32 + quad * 8);
            floatx4 z = {};
            Sc[nt] = __builtin_amdgcn_mfma_f32_16x16x32_bf16(bk, aq, z, 0, 0, 0);
        }
        float mx = -3e38f;
        const ushort_t* bq = bb + q0;
        if (!hm) {
#pragma unroll
            for (int nt = 0; nt < 16; ++nt)
#pragma unroll
                for (int r = 0; r < 4; ++r) {
                    float s = fmaf(Sc[nt][r], scale, b2f(bq[(nt * 16 + quad * 4 + r) << 8]));
                    Sc[nt][r] = s; mx = fmaxf(mx, s);
                }
        } else {
            int myreg = reg_s[q0 + l15];
#pragma unroll
            for (int nt = 0; nt < 16; ++nt)
#pragma unroll
                for (int r = 0; r < 4; ++r) {
                    int key = nt * 16 + quad * 4 + r;
                    float s = fmaf(Sc[nt][r], scale, b2f(bq[key << 8]));
                    s = (reg_s[key] == myreg) ? s : -1e9f;
                    Sc[nt][r] = s; mx = fmaxf(mx, s);
                }
        }
        mx = fmaxf(mx, __shfl_xor(mx, 16, 64));
        mx = fmaxf(mx, __shfl_xor(mx, 32, 64));
        float lsum = 0.f;
#pragma unroll
        for (int nt = 0; nt < 16; ++nt)
#pragma unroll
            for (int r = 0; r < 4; ++r) {
                float p = __expf(Sc[nt][r] - mx);
                lsum += p; Sc[nt][r] = p;
            }
        lsum += __shfl_xor(lsum, 16, 64);
        lsum += __shfl_xor(lsum, 32, 64);
        float inv = 1.f / lsum;
        // O^T = V^T @ P^T : lane-local P packing via v_perm (verified layout)
        floatx4 oc[2] = {{0.f,0.f,0.f,0.f},{0.f,0.f,0.f,0.f}};
        const ushort_t* vr = Vt + quad * 4;
#pragma unroll
        for (int kt = 0; kt < 8; ++kt) {
            union { uint_t u[4]; bf16x8 v; } bp;
            bp.u[0] = __builtin_amdgcn_perm(__float_as_uint(Sc[2*kt][1]),   __float_as_uint(Sc[2*kt][0]),   0x07060302u);
            bp.u[1] = __builtin_amdgcn_perm(__float_as_uint(Sc[2*kt][3]),   __float_as_uint(Sc[2*kt][2]),   0x07060302u);
            bp.u[2] = __builtin_amdgcn_perm(__float_as_uint(Sc[2*kt+1][1]), __float_as_uint(Sc[2*kt+1][0]), 0x07060302u);
            bp.u[3] = __builtin_amdgcn_perm(__float_as_uint(Sc[2*kt+1][3]), __float_as_uint(Sc[2*kt+1][2]), 0x07060302u);
#pragma unroll
            for (int ct = 0; ct < 2; ++ct) {
                const ushort_t* vrow = vr + (ct * 16 + l15) * VTS;
                union { unsigned long long l[2]; bf16x8 v; } av;
                av.l[0] = *(const unsigned long long*)(vrow + 2 * kt * 16);
                av.l[1] = *(const unsigned long long*)(vrow + 2 * kt * 16 + 16);
                oc[ct] = __builtin_amdgcn_mfma_f32_16x16x32_bf16(av.v, bp.v, oc[ct], 0, 0, 0);
            }
        }
        // stage O tile (query-row major) then coalesced 1KB store
#pragma unroll
        for (int ct = 0; ct < 2; ++ct) {
            uint2 st;
            st.x = (uint_t)f2b(oc[ct][0] * inv) | ((uint_t)f2b(oc[ct][1] * inv) << 16);
            st.y = (uint_t)f2b(oc[ct][2] * inv) | ((uint_t)f2b(oc[ct][3] * inv) << 16);
            *(uint2*)(ow + l15 * OLS + ct * 16 + quad * 4) = st;
        }
        __builtin_amdgcn_s_waitcnt(0xC07F);       // lgkmcnt(0)
        __builtin_amdgcn_wave_barrier();
        {
            int qr = lane >> 2, chk = (lane & 3) * 8;
            uint4 val = *(const uint4*)(ow + qr * OLS + chk);
            *(uint4*)(Og + (size_t)(q0 + qr) * 32 + chk) = val;
        }
        __builtin_amdgcn_wave_barrier();
    }
}

// ---------------- final permute: y (tok, C) fp32 -> out (B, C, D, Hp, Wp) fp32
__global__ void out_permute(const float* __restrict__ Y, float* __restrict__ Out) {
    __shared__ float tile[64][65];
    const int t0 = blockIdx.x * 64;
    const int c0 = blockIdx.y * 64;
    const int tid = threadIdx.x;
    const int a = tid >> 6;
    const int bx = tid & 63;
#pragma unroll
    for (int s8 = 0; s8 < 16; ++s8) {
        int tt = a + s8 * 4;
        tile[tt][bx] = Y[(long)(t0 + tt) * 256 + c0 + bx];
    }
    __syncthreads();
#pragma unroll
    for (int s8 = 0; s8 < 16; ++s8) {
        int cc = a + s8 * 4;
        int tok = t0 + bx;
        int bb = tok / 25088;
        int rem = tok - bb * 25088;
        Out[((long)(bb * 256 + c0 + cc)) * 25088 + rem] = tile[bx][cc];
    }
}

extern "C" void kernel_launch(void* const* d_in, const int* in_sizes, int n_in,
                              void* d_out, int out_size, void* d_ws, size_t ws_size,
                              hipStream_t stream) {
    (void)in_sizes; (void)n_in; (void)out_size; (void)ws_size;
    const float* x        = (const float*)d_in[0];
    const float* conv_w   = (const float*)d_in[1];
    const float* conv_b   = (const float*)d_in[2];
    const float* ln1_s    = (const float*)d_in[3];
    const float* ln1_b    = (const float*)d_in[4];
    const float* qkv_w    = (const float*)d_in[5];
    const float* out_w    = (const float*)d_in[6];
    const float* out_b    = (const float*)d_in[7];
    const float* bias_tab = (const float*)d_in[8];
    const float* ln2_s    = (const float*)d_in[9];
    const float* ln2_b    = (const float*)d_in[10];
    const float* fc1_w    = (const float*)d_in[11];
    const float* fc1_b    = (const float*)d_in[12];
    const float* fc2_w    = (const float*)d_in[13];
    const float* fc2_b    = (const float*)d_in[14];
    float* out = (float*)d_out;

    char* ws = (char*)d_ws;
    float*    y    = (float*)ws;    ws += (size_t)NTOK * 256 * 4;   // fp32 residual stream
    ushort_t* big  = (ushort_t*)ws; ws += (size_t)NTOK * 1024 * 2;  // qkv/h1/im2row bf16
    ushort_t* xob  = (ushort_t*)ws; ws += (size_t)NTOK * 256 * 2;   // LN out / attn out bf16
    ushort_t* bt_qkv = (ushort_t*)ws; ws += (size_t)4 * 768 * 256 * 2;
    ushort_t* bt_out = (ushort_t*)ws; ws += (size_t)4 * 256 * 256 * 2;
    ushort_t* bt_fc1 = (ushort_t*)ws; ws += (size_t)4 * 1024 * 256 * 2;
    ushort_t* bt_fc2 = (ushort_t*)ws; ws += (size_t)4 * 256 * 1024 * 2;
    ushort_t* cw_bf  = (ushort_t*)ws; ws += (size_t)256 * 64 * 2;
    ushort_t* Bx     = (ushort_t*)ws; ws += (size_t)4 * 8 * 256 * 256 * 2;

    transpose_w<<<dim3((256 * 768 + 255) / 256, 4), 256, 0, stream>>>(qkv_w, bt_qkv, 256, 768);
    transpose_w<<<dim3((256 * 256 + 255) / 256, 4), 256, 0, stream>>>(out_w, bt_out, 256, 256);
    transpose_w<<<dim3((256 * 1024 + 255) / 256, 4), 256, 0, stream>>>(fc1_w, bt_fc1, 256, 1024);
    transpose_w<<<dim3((1024 * 256 + 255) / 256, 4), 256, 0, stream>>>(fc2_w, bt_fc2, 1024, 256);
    expand_bias<<<dim3(256, 8, 4), 256, 0, stream>>>(bias_tab, Bx);

    // conv as GEMM: conv_w (O,I,1,4,4) is already BT[256][64] row-major — cast only
    cast_bf16<<<(256 * 64 + 255) / 256, 256, 0, stream>>>(conv_w, cw_bf, 256 * 64);
    im2row<<<NTOK * 16 / 256, 256, 0, stream>>>(x, big);
    gemm_bt<<<dim3(NTOK / 128, 2), 256, 0, stream>>>(
        big, cw_bf, NTOK, 256, 64, conv_b, 3, nullptr, y, 0, 0);

    for (int i = 0; i < 4; ++i) {
        int sh = i & 1;
        ln_kernel<<<NTOK / 4, 256, 0, stream>>>(y, xob, ln1_s + i * 256, ln1_b + i * 256);
        // QKV -> big [tok][768], coalesced
        gemm_bt<<<dim3(NTOK / 128, 6), 256, 0, stream>>>(
            xob, bt_qkv + (size_t)i * 768 * 256, NTOK, 768, 256, nullptr, 0, big, nullptr, 0, 0);
        // attention: gathers QKV, writes head-split window-ordered O into xob
        attn_mfma<<<dim3(NWIN, 8, 2), 256, 0, stream>>>(
            big, xob, Bx + (size_t)i * 8 * 65536, sh);
        // out-proj: A head-split window-ordered; un-permute rows into y
        gemm_bt<<<dim3(NTOK / 128, 2), 256, 0, stream>>>(
            xob, bt_out + (size_t)i * 256 * 256, NTOK, 256, 256, out_b + i * 256, 5, nullptr, y, sh, 1);
        ln_kernel<<<NTOK / 4, 256, 0, stream>>>(y, xob, ln2_s + i * 256, ln2_b + i * 256);
        gemm_bt<<<dim3(NTOK / 128, 8), 256, 0, stream>>>(
            xob, bt_fc1 + (size_t)i * 1024 * 256, NTOK, 1024, 256, fc1_b + i * 1024, 1, big, nullptr, 0, 0);
        gemm_bt<<<dim3(NTOK / 128, 2), 256, 0, stream>>>(
            big, bt_fc2 + (size_t)i * 256 * 1024, NTOK, 256, 1024, fc2_b + i * 256, 2, nullptr, y, 0, 0);
    }

    out_permute<<<dim3(NTOK / 64, 4), 256, 0, stream>>>(y, out);
}

// Round 7
// 1476.920 us; speedup vs baseline: 1.5868x; 1.0590x over previous
//
#include <hip/hip_runtime.h>

typedef unsigned short ushort_t;
typedef unsigned int   uint_t;

#define NTOK 50176          // B*D*Hp*Wp = 2*8*56*56
#define NWIN 98             // (8/4)*(56/8)*(56/8)
#define NBIAS 1575          // 7*15*15

typedef __attribute__((ext_vector_type(8))) short bf16x8;
typedef __attribute__((ext_vector_type(4))) float floatx4;

static __device__ __forceinline__ float b2f(ushort_t u) {
    return __uint_as_float(((uint_t)u) << 16);
}
static __device__ __forceinline__ ushort_t f2b(float f) {
    union { float f; uint_t u; } v; v.f = f;
    uint_t u = v.u + 0x7fffu + ((v.u >> 16) & 1u);
    return (ushort_t)(u >> 16);
}

// window-ordered index -> token (B,D,Hp,Wp row-major), with optional shift roll
static __device__ __forceinline__ int wtok2tok(int wt, int sh) {
    int b = wt / 25088, rem = wt - b * 25088;
    int win = rem >> 8, pos = rem & 255;
    int wd = win / 49, r1 = win - wd * 49;
    int wh = r1 / 7, ww = r1 - wh * 7;
    int d = wd * 4 + (pos >> 6), h = wh * 8 + ((pos >> 3) & 7), w = ww * 8 + (pos & 7);
    if (sh) { d = (d + 2) & 7; h += 4; if (h >= 56) h -= 56; w += 4; if (w >= 56) w -= 56; }
    return (b * 8 + d) * 3136 + h * 56 + w;
}

// ---------------- weight transpose + fp32->bf16 cast: dst[n*K+k] = bf16(src[k*N+n])
__global__ void transpose_w(const float* __restrict__ src, ushort_t* __restrict__ dst,
                            int K, int N) {
    long base = (long)blockIdx.y * K * N;
    int idx = blockIdx.x * 256 + threadIdx.x;
    if (idx < K * N) {
        int k = idx / N, n = idx - k * N;
        dst[base + (long)n * K + k] = f2b(src[base + idx]);
    }
}

// ---------------- elementwise fp32 -> bf16 cast
__global__ void cast_bf16(const float* __restrict__ src, ushort_t* __restrict__ dst, int n) {
    int i = blockIdx.x * 256 + threadIdx.x;
    if (i < n) dst[i] = f2b(src[i]);
}

// ---------------- expand relative-position bias: Bx[layer][hd][key j][query i] bf16
__global__ void expand_bias(const float* __restrict__ bias_tab, ushort_t* __restrict__ Bx) {
    int j = blockIdx.x, hd = blockIdx.y, l = blockIdx.z;
    int i = threadIdx.x;
    int rd = (i >> 6) - (j >> 6) + 3;
    int rh = ((i >> 3) & 7) - ((j >> 3) & 7) + 7;
    int rw = (i & 7) - (j & 7) + 7;
    int idx = rd * 225 + rh * 15 + rw;
    Bx[((((size_t)l * 8 + hd) << 8) + j) * 256 + i] =
        f2b(bias_tab[((size_t)l * NBIAS + idx) * 8 + hd]);
}

// ---------------- im2row: A[tok, 64] bf16 patch matrix from X (NCDHW fp32)
__global__ void im2row(const float* __restrict__ X, ushort_t* __restrict__ A) {
    int idx = blockIdx.x * 256 + threadIdx.x;   // NTOK*16 total
    int t = idx >> 4;
    int k = idx & 15;
    int ic = k >> 2, kh = k & 3;
    int w = t % 56, h = (t / 56) % 56, d = (t / 3136) % 8, b = t / 25088;
    long xi = (((long)(b * 4 + ic) * 8 + d) * 224 + (h * 4 + kh)) * 224 + w * 4;
    float4 u = *(const float4*)(X + xi);
    ushort_t* ap = A + (long)t * 64 + ic * 16 + kh * 4;
    ap[0] = f2b(u.x); ap[1] = f2b(u.y); ap[2] = f2b(u.z); ap[3] = f2b(u.w);
}

// ---------------- LayerNorm: 4 tokens per block, one wave per token; fp32 in, bf16 out
__global__ void ln_kernel(const float* __restrict__ Y, ushort_t* __restrict__ Xn,
                          const float* __restrict__ S, const float* __restrict__ Bb) {
    int wv = threadIdx.x >> 6, lane = threadIdx.x & 63;
    long t = (long)blockIdx.x * 4 + wv;
    const float* y = Y + t * 256;
    float v[4], s = 0.f, s2 = 0.f;
#pragma unroll
    for (int r = 0; r < 4; ++r) { v[r] = y[lane + 64 * r]; s += v[r]; s2 += v[r] * v[r]; }
#pragma unroll
    for (int off = 32; off; off >>= 1) { s += __shfl_xor(s, off, 64); s2 += __shfl_xor(s2, off, 64); }
    float mu = s * (1.f / 256.f);
    float var = s2 * (1.f / 256.f) - mu * mu;
    float rstd = rsqrtf(var + 1e-5f);
#pragma unroll
    for (int r = 0; r < 4; ++r) {
        int c = lane + 64 * r;
        Xn[t * 256 + c] = f2b((v[r] - mu) * rstd * S[c] + Bb[c]);
    }
}

// ---------------- GEMM: C[M,N] = A[M,K] @ B[K,N] via BT[N,K]; m97-style 128x128 tile
// mode 0: bf16 store; 1: bias+gelu bf16; 2: Y += acc+bias (fp32); 3: Y = acc+bias (fp32);
// 4: head-split store C[((c>>5)*NTOK + row)*32 + (c&31)] (no permute);
// 5: Y[tok] += acc+bias, rows un-permuted from window order (sh)
// asplit: A stored head-split [c>>5][NTOK][32] instead of row-major [M][K]
__global__ __launch_bounds__(256, 2) void gemm_bt(
    const ushort_t* __restrict__ A, const ushort_t* __restrict__ BT,
    int M, int N, int K,
    const float* __restrict__ bias, int mode,
    ushort_t* __restrict__ C, float* __restrict__ Y, int sh, int asplit) {
    __shared__ ushort_t As[128 * 32];
    __shared__ ushort_t Bs[128 * 32];
    const int tid = threadIdx.x;
    const int wv = tid >> 6;
    const int lane = tid & 63;
    const int quad = lane >> 4;
    const int l15 = lane & 15;
    const long m0 = (long)blockIdx.x * 128;
    const long n0 = (long)blockIdx.y * 128;
    const int wm = (wv & 1) * 64;
    const int wn = (wv >> 1) * 64;
    const int r_loc = lane >> 2;
    const int k_loc = (lane & 3) * 8;

    floatx4 acc[4][4] = {};

    const ushort_t* Ab = A + m0 * K;
    const ushort_t* Bb = BT + n0 * K;

    for (int kt = 0; kt < K; kt += 32) {
#pragma unroll
        for (int q = 0; q < 2; ++q) {
            int slot = wv * 2 + q;
            int row = slot * 16 + r_loc;
            const ushort_t* asrc = asplit
                ? A + ((size_t)(kt >> 5) * NTOK + m0 + row) * 32 + k_loc
                : Ab + (long)row * K + kt + k_loc;
            __builtin_amdgcn_global_load_lds(
                (const __attribute__((address_space(1))) void*)asrc,
                (__attribute__((address_space(3))) void*)(As + slot * 512), 16, 0, 0);
            __builtin_amdgcn_global_load_lds(
                (const __attribute__((address_space(1))) void*)(Bb + (long)row * K + kt + k_loc),
                (__attribute__((address_space(3))) void*)(Bs + slot * 512), 16, 0, 0);
        }
        __syncthreads();
        bf16x8 af[4], bfr[4];
#pragma unroll
        for (int i = 0; i < 4; ++i) {
            af[i]  = *(const bf16x8*)(As + (wm + i * 16 + l15) * 32 + quad * 8);
            bfr[i] = *(const bf16x8*)(Bs + (wn + i * 16 + l15) * 32 + quad * 8);
        }
#pragma unroll
        for (int mi = 0; mi < 4; ++mi)
#pragma unroll
            for (int ni = 0; ni < 4; ++ni)
                acc[mi][ni] = __builtin_amdgcn_mfma_f32_16x16x32_bf16(af[mi], bfr[ni], acc[mi][ni], 0, 0, 0);
        __syncthreads();
    }

    if (mode == 2) {
#pragma unroll
        for (int mi = 0; mi < 4; ++mi)
#pragma unroll
            for (int ni = 0; ni < 4; ++ni) {
                long col = n0 + wn + ni * 16 + l15;
                float bv = bias[col];
#pragma unroll
                for (int r = 0; r < 4; ++r) {
                    long row = m0 + wm + mi * 16 + quad * 4 + r;
                    Y[row * N + col] += acc[mi][ni][r] + bv;
                }
            }
    } else if (mode == 3) {
#pragma unroll
        for (int mi = 0; mi < 4; ++mi)
#pragma unroll
            for (int ni = 0; ni < 4; ++ni) {
                long col = n0 + wn + ni * 16 + l15;
                float bv = bias[col];
#pragma unroll
                for (int r = 0; r < 4; ++r) {
                    long row = m0 + wm + mi * 16 + quad * 4 + r;
                    Y[row * N + col] = acc[mi][ni][r] + bv;
                }
            }
    } else if (mode == 4) {
#pragma unroll
        for (int mi = 0; mi < 4; ++mi)
#pragma unroll
            for (int ni = 0; ni < 4; ++ni) {
                int c = (int)(n0 + wn + ni * 16 + l15);
                int seg = c >> 5, ch = c & 31;
                ushort_t* base = C + ((size_t)seg * NTOK) * 32 + ch;
#pragma unroll
                for (int r = 0; r < 4; ++r) {
                    size_t row = (size_t)(m0 + wm + mi * 16 + quad * 4 + r);
                    base[row * 32] = f2b(acc[mi][ni][r]);
                }
            }
    } else if (mode == 5) {
#pragma unroll
        for (int mi = 0; mi < 4; ++mi) {
            int tk[4];
#pragma unroll
            for (int r = 0; r < 4; ++r)
                tk[r] = wtok2tok((int)(m0 + wm + mi * 16 + quad * 4 + r), sh);
#pragma unroll
            for (int ni = 0; ni < 4; ++ni) {
                long col = n0 + wn + ni * 16 + l15;
                float bv = bias[col];
#pragma unroll
                for (int r = 0; r < 4; ++r)
                    Y[(size_t)tk[r] * N + col] += acc[mi][ni][r] + bv;
            }
        }
    } else {
#pragma unroll
        for (int mi = 0; mi < 4; ++mi)
#pragma unroll
            for (int ni = 0; ni < 4; ++ni) {
                long col = n0 + wn + ni * 16 + l15;
                float bv = bias ? bias[col] : 0.f;
#pragma unroll
                for (int r = 0; r < 4; ++r) {
                    long row = m0 + wm + mi * 16 + quad * 4 + r;
                    float v = acc[mi][ni][r] + bv;
                    if (mode == 1) {
                        float x3 = v * v * v;
                        v = 0.5f * v * (1.f + tanhf(0.7978845608028654f * (v + 0.044715f * x3)));
                    }
                    C[row * N + col] = f2b(v);
                }
            }
    }
}

// ---------------- MFMA window attention v4: S^T core; head-split QKV; hd->XCD affinity.
// QKV head-split [mat*8+hd][NTOK][32] (plain token rows); O head-split window-ordered
// [hd][NTOK][32]; Bx bf16 expanded per (layer,hd).
#define VTS 268
#define OLS 34
__global__ __launch_bounds__(256, 4) void attn_mfma(
    const ushort_t* __restrict__ QKV, ushort_t* __restrict__ O,
    const ushort_t* __restrict__ Bx, int shifted) {
    __shared__ ushort_t Ks[256 * 32];      // K [tok][32]
    __shared__ ushort_t Vt[32 * VTS];      // V^T [ch][tok]
    __shared__ ushort_t Ol[4 * 16 * OLS];  // per-wave O staging
    __shared__ int tok_s[256];
    __shared__ int reg_s[256];

    const int tid = threadIdx.x;
    const int wv = tid >> 6;
    const int lane = tid & 63;
    const int quad = lane >> 4;
    const int l15 = lane & 15;
    const int hd = blockIdx.x, win = blockIdx.y, b = blockIdx.z;   // hd -> XCD (id%8)
    const int wd = win / 49, r1w = win - wd * 49;
    const int wh = r1w / 7, ww = r1w - wh * 7;
    const size_t wbase = ((size_t)b * 98 + win) * 256;
    const ushort_t* Qg = QKV + (size_t)hd * NTOK * 32;
    const ushort_t* Kg = QKV + (size_t)(8 + hd) * NTOK * 32;
    const ushort_t* Vg = QKV + (size_t)(16 + hd) * NTOK * 32;

    {   // token ids (with shift roll) + region ids
        int pos = tid;
        int d = wd * 4 + (pos >> 6), h = wh * 8 + ((pos >> 3) & 7), w = ww * 8 + (pos & 7);
        int rd = d < 4 ? 0 : (d < 6 ? 1 : 2);
        int rh = h < 48 ? 0 : (h < 52 ? 1 : 2);
        int rw = w < 48 ? 0 : (w < 52 ? 1 : 2);
        reg_s[pos] = rd * 9 + rh * 3 + rw;
        int d0 = d, h0 = h, w0 = w;
        if (shifted) { d0 = (d + 2) & 7; h0 = h + 4; if (h0 >= 56) h0 -= 56; w0 = w + 4; if (w0 >= 56) w0 -= 56; }
        tok_s[pos] = (b * 8 + d0) * 3136 + h0 * 56 + w0;
    }
    __syncthreads();
    {   // stage K via global_load_lds: lane -> token (lane>>2), 16B chunk (lane&3)
#pragma unroll
        for (int q = 0; q < 4; ++q) {
            int t = wv * 64 + q * 16 + (lane >> 2);
            const ushort_t* src = Kg + (size_t)tok_s[t] * 32 + (lane & 3) * 8;
            __builtin_amdgcn_global_load_lds(
                (const __attribute__((address_space(1))) void*)src,
                (__attribute__((address_space(3))) void*)(Ks + wv * 2048 + q * 512), 16, 0, 0);
        }
        // stage V^T: 16B reads (512B-contiguous runs), scatter to LDS
#pragma unroll
        for (int p = 0; p < 4; ++p) {
            int u = tid + p * 256;
            int tok = u >> 2, chb = (u & 3) * 8;
            uint4 vv = *(const uint4*)(Vg + (size_t)tok_s[tok] * 32 + chb);
            uint_t uu[4] = {vv.x, vv.y, vv.z, vv.w};
#pragma unroll
            for (int e = 0; e < 4; ++e) {
                Vt[(chb + 2 * e) * VTS + tok]     = (ushort_t)(uu[e] & 0xffffu);
                Vt[(chb + 2 * e + 1) * VTS + tok] = (ushort_t)(uu[e] >> 16);
            }
        }
    }
    __syncthreads();

    const int hm = shifted && (wd == 1 || wh == 6 || ww == 6);
    const float scale = 0.17677669529663687f;
    const ushort_t* bb = Bx + ((size_t)hd << 16) + l15;
    ushort_t* ow = Ol + wv * 16 * OLS;
    ushort_t* Og = O + ((size_t)hd * NTOK + wbase) * 32;

    for (int rg = 0; rg < 4; ++rg) {
        const int q0 = (wv * 4 + rg) * 16;
        bf16x8 aq;
        {
            union { uint4 u; bf16x8 v; } cv;
            cv.u = *(const uint4*)(Qg + (size_t)tok_s[q0 + l15] * 32 + quad * 8);
            aq = cv.v;
        }
        // S^T = K @ Q^T : row = key, col = query
        floatx4 Sc[16];
#pragma unroll
        for (int nt = 0; nt < 16; ++nt) {
            bf16x8 bk = *(const bf16x8*)(Ks + (nt * 16 + l15) * 32 + quad * 8);
            floatx4 z = {};
            Sc[nt] = __builtin_amdgcn_mfma_f32_16x16x32_bf16(bk, aq, z, 0, 0, 0);
        }
        float mx = -3e38f;
        const ushort_t* bq = bb + q0;
        if (!hm) {
#pragma unroll
            for (int nt = 0; nt < 16; ++nt)
#pragma unroll
                for (int r = 0; r < 4; ++r) {
                    float s = fmaf(Sc[nt][r], scale, b2f(bq[(nt * 16 + quad * 4 + r) << 8]));
                    Sc[nt][r] = s; mx = fmaxf(mx, s);
                }
        } else {
            int myreg = reg_s[q0 + l15];
#pragma unroll
            for (int nt = 0; nt < 16; ++nt)
#pragma unroll
                for (int r = 0; r < 4; ++r) {
                    int key = nt * 16 + quad * 4 + r;
                    float s = fmaf(Sc[nt][r], scale, b2f(bq[key << 8]));
                    s = (reg_s[key] == myreg) ? s : -1e9f;
                    Sc[nt][r] = s; mx = fmaxf(mx, s);
                }
        }
        mx = fmaxf(mx, __shfl_xor(mx, 16, 64));
        mx = fmaxf(mx, __shfl_xor(mx, 32, 64));
        float lsum = 0.f;
#pragma unroll
        for (int nt = 0; nt < 16; ++nt)
#pragma unroll
            for (int r = 0; r < 4; ++r) {
                float p = __expf(Sc[nt][r] - mx);
                lsum += p; Sc[nt][r] = p;
            }
        lsum += __shfl_xor(lsum, 16, 64);
        lsum += __shfl_xor(lsum, 32, 64);
        float inv = 1.f / lsum;
        // O^T = V^T @ P^T : lane-local P packing via v_perm (verified layout)
        floatx4 oc[2] = {{0.f,0.f,0.f,0.f},{0.f,0.f,0.f,0.f}};
        const ushort_t* vr = Vt + quad * 4;
#pragma unroll
        for (int kt = 0; kt < 8; ++kt) {
            union { uint_t u[4]; bf16x8 v; } bp;
            bp.u[0] = __builtin_amdgcn_perm(__float_as_uint(Sc[2*kt][1]),   __float_as_uint(Sc[2*kt][0]),   0x07060302u);
            bp.u[1] = __builtin_amdgcn_perm(__float_as_uint(Sc[2*kt][3]),   __float_as_uint(Sc[2*kt][2]),   0x07060302u);
            bp.u[2] = __builtin_amdgcn_perm(__float_as_uint(Sc[2*kt+1][1]), __float_as_uint(Sc[2*kt+1][0]), 0x07060302u);
            bp.u[3] = __builtin_amdgcn_perm(__float_as_uint(Sc[2*kt+1][3]), __float_as_uint(Sc[2*kt+1][2]), 0x07060302u);
#pragma unroll
            for (int ct = 0; ct < 2; ++ct) {
                const ushort_t* vrow = vr + (ct * 16 + l15) * VTS;
                union { unsigned long long l[2]; bf16x8 v; } av;
                av.l[0] = *(const unsigned long long*)(vrow + 2 * kt * 16);
                av.l[1] = *(const unsigned long long*)(vrow + 2 * kt * 16 + 16);
                oc[ct] = __builtin_amdgcn_mfma_f32_16x16x32_bf16(av.v, bp.v, oc[ct], 0, 0, 0);
            }
        }
        // stage O tile (query-row major) then coalesced 1KB store
#pragma unroll
        for (int ct = 0; ct < 2; ++ct) {
            uint2 st;
            st.x = (uint_t)f2b(oc[ct][0] * inv) | ((uint_t)f2b(oc[ct][1] * inv) << 16);
            st.y = (uint_t)f2b(oc[ct][2] * inv) | ((uint_t)f2b(oc[ct][3] * inv) << 16);
            *(uint2*)(ow + l15 * OLS + ct * 16 + quad * 4) = st;
        }
        __builtin_amdgcn_s_waitcnt(0xC07F);       // lgkmcnt(0)
        __builtin_amdgcn_wave_barrier();
        {
            int qr = lane >> 2, chk = (lane & 3) * 8;
            uint4 val = *(const uint4*)(ow + qr * OLS + chk);
            *(uint4*)(Og + (size_t)(q0 + qr) * 32 + chk) = val;
        }
        __builtin_amdgcn_wave_barrier();
    }
}

// ---------------- final permute: y (tok, C) fp32 -> out (B, C, D, Hp, Wp) fp32
__global__ void out_permute(const float* __restrict__ Y, float* __restrict__ Out) {
    __shared__ float tile[64][65];
    const int t0 = blockIdx.x * 64;
    const int c0 = blockIdx.y * 64;
    const int tid = threadIdx.x;
    const int a = tid >> 6;
    const int bx = tid & 63;
#pragma unroll
    for (int s8 = 0; s8 < 16; ++s8) {
        int tt = a + s8 * 4;
        tile[tt][bx] = Y[(long)(t0 + tt) * 256 + c0 + bx];
    }
    __syncthreads();
#pragma unroll
    for (int s8 = 0; s8 < 16; ++s8) {
        int cc = a + s8 * 4;
        int tok = t0 + bx;
        int bb = tok / 25088;
        int rem = tok - bb * 25088;
        Out[((long)(bb * 256 + c0 + cc)) * 25088 + rem] = tile[bx][cc];
    }
}

extern "C" void kernel_launch(void* const* d_in, const int* in_sizes, int n_in,
                              void* d_out, int out_size, void* d_ws, size_t ws_size,
                              hipStream_t stream) {
    (void)in_sizes; (void)n_in; (void)out_size; (void)ws_size;
    const float* x        = (const float*)d_in[0];
    const float* conv_w   = (const float*)d_in[1];
    const float* conv_b   = (const float*)d_in[2];
    const float* ln1_s    = (const float*)d_in[3];
    const float* ln1_b    = (const float*)d_in[4];
    const float* qkv_w    = (const float*)d_in[5];
    const float* out_w    = (const float*)d_in[6];
    const float* out_b    = (const float*)d_in[7];
    const float* bias_tab = (const float*)d_in[8];
    const float* ln2_s    = (const float*)d_in[9];
    const float* ln2_b    = (const float*)d_in[10];
    const float* fc1_w    = (const float*)d_in[11];
    const float* fc1_b    = (const float*)d_in[12];
    const float* fc2_w    = (const float*)d_in[13];
    const float* fc2_b    = (const float*)d_in[14];
    float* out = (float*)d_out;

    char* ws = (char*)d_ws;
    float*    y    = (float*)ws;    ws += (size_t)NTOK * 256 * 4;   // fp32 residual stream
    ushort_t* big  = (ushort_t*)ws; ws += (size_t)NTOK * 1024 * 2;  // qkv(head-split)/h1/im2row
    ushort_t* xob  = (ushort_t*)ws; ws += (size_t)NTOK * 256 * 2;   // LN out / attn out bf16
    ushort_t* bt_qkv = (ushort_t*)ws; ws += (size_t)4 * 768 * 256 * 2;
    ushort_t* bt_out = (ushort_t*)ws; ws += (size_t)4 * 256 * 256 * 2;
    ushort_t* bt_fc1 = (ushort_t*)ws; ws += (size_t)4 * 1024 * 256 * 2;
    ushort_t* bt_fc2 = (ushort_t*)ws; ws += (size_t)4 * 256 * 1024 * 2;
    ushort_t* cw_bf  = (ushort_t*)ws; ws += (size_t)256 * 64 * 2;
    ushort_t* Bx     = (ushort_t*)ws; ws += (size_t)4 * 8 * 256 * 256 * 2;

    transpose_w<<<dim3((256 * 768 + 255) / 256, 4), 256, 0, stream>>>(qkv_w, bt_qkv, 256, 768);
    transpose_w<<<dim3((256 * 256 + 255) / 256, 4), 256, 0, stream>>>(out_w, bt_out, 256, 256);
    transpose_w<<<dim3((256 * 1024 + 255) / 256, 4), 256, 0, stream>>>(fc1_w, bt_fc1, 256, 1024);
    transpose_w<<<dim3((1024 * 256 + 255) / 256, 4), 256, 0, stream>>>(fc2_w, bt_fc2, 1024, 256);
    expand_bias<<<dim3(256, 8, 4), 256, 0, stream>>>(bias_tab, Bx);

    // conv as GEMM: conv_w (O,I,1,4,4) is already BT[256][64] row-major — cast only
    cast_bf16<<<(256 * 64 + 255) / 256, 256, 0, stream>>>(conv_w, cw_bf, 256 * 64);
    im2row<<<NTOK * 16 / 256, 256, 0, stream>>>(x, big);
    gemm_bt<<<dim3(NTOK / 128, 2), 256, 0, stream>>>(
        big, cw_bf, NTOK, 256, 64, conv_b, 3, nullptr, y, 0, 0);

    for (int i = 0; i < 4; ++i) {
        int sh = i & 1;
        ln_kernel<<<NTOK / 4, 256, 0, stream>>>(y, xob, ln1_s + i * 256, ln1_b + i * 256);
        // QKV -> big, head-split [mat*8+hd][NTOK][32] (coalesced, no permute)
        gemm_bt<<<dim3(NTOK / 128, 6), 256, 0, stream>>>(
            xob, bt_qkv + (size_t)i * 768 * 256, NTOK, 768, 256, nullptr, 4, big, nullptr, 0, 0);
        // attention: hd -> XCD affinity; writes head-split window-ordered O into xob
        attn_mfma<<<dim3(8, NWIN, 2), 256, 0, stream>>>(
            big, xob, Bx + (size_t)i * 8 * 65536, sh);
        // out-proj: A head-split window-ordered; un-permute rows into y
        gemm_bt<<<dim3(NTOK / 128, 2), 256, 0, stream>>>(
            xob, bt_out + (size_t)i * 256 * 256, NTOK, 256, 256, out_b + i * 256, 5, nullptr, y, sh, 1);
        ln_kernel<<<NTOK / 4, 256, 0, stream>>>(y, xob, ln2_s + i * 256, ln2_b + i * 256);
        gemm_bt<<<dim3(NTOK / 128, 8), 256, 0, stream>>>(
            xob, bt_fc1 + (size_t)i * 1024 * 256, NTOK, 1024, 256, fc1_b + i * 1024, 1, big, nullptr, 0, 0);
        gemm_bt<<<dim3(NTOK / 128, 2), 256, 0, stream>>>(
            big, bt_fc2 + (size_t)i * 256 * 1024, NTOK, 256, 1024, fc2_b + i * 256, 2, nullptr, y, 0, 0);
    }

    out_permute<<<dim3(NTOK / 64, 4), 256, 0, stream>>>(y, out);
}